// Round 1
// baseline (460.903 us; speedup 1.0000x reference)
//
#include <hip/hip_runtime.h>
#include <cstdint>
#include <cstddef>

#define N_NODES 8192
#define NFEAT   512
#define NHID    128

// ---------------------------------------------------------------------------
// Workspace layout (bytes):
//   [0]          bitmap   : 8192*8192/8      = 8388608   (zeroed each call)
//   [8388608]    cnt      : 8192*4           = 32768     (zeroed)
//   [8421376]    fill     : 8192*4           = 32768     (zeroed)
//   [8454144]    colsum   : 128*4 -> 512     (zeroed, kept for layout)
//   ZERO_BYTES = 8454656
//   [8454656]    rep_pre  : 8192*256*4 = 8388608
//   [16843264]   rep      : 8192*256*4 = 8388608
//   [25231872]   u        : 8192*4 -> 32768
//   [25264640]   v        : 8192*4 -> 32768
//   [25297408]   rowptr   : 8193*4 -> 33024
//   [25330432]   flag     : 262144
//   [25592576]   colidx   : 262144*4 = 1048576
//   [26641152]   colpart  : 64*128*4 = 32768
//   end ~ 26.7 MB
// ---------------------------------------------------------------------------

// ============ K1: rep_pre = x @ [gc_W | gct_W]  (f32 tiled GEMM) ============
__global__ __launch_bounds__(256)
void gemm1_kernel(const float* __restrict__ x,
                  const float* __restrict__ gcW,
                  const float* __restrict__ gctW,
                  float* __restrict__ rep_pre)
{
    const int bx  = blockIdx.x;         // 0..3  (64-col blocks of 256)
    const int by  = blockIdx.y;         // 0..127 (64-row blocks of 8192)
    const int tid = threadIdx.x;
    const int tx  = tid & 15;
    const int ty  = tid >> 4;
    const float* B = (bx < 2) ? gcW : gctW;
    const int n0   = (bx & 1) * 64;

    __shared__ float As[64][17];
    __shared__ float Bs[16][64];

    float acc[4][4];
#pragma unroll
    for (int i = 0; i < 4; ++i)
#pragma unroll
        for (int j = 0; j < 4; ++j) acc[i][j] = 0.f;

    for (int kb = 0; kb < NFEAT / 16; ++kb) {
        const int k0 = kb * 16;
        {   // stage A tile 64x16 (one float4 per thread)
            const int r  = tid >> 2;
            const int kk = (tid & 3) * 4;
            const float4 av = *reinterpret_cast<const float4*>(
                x + (size_t)(by * 64 + r) * NFEAT + k0 + kk);
            As[r][kk + 0] = av.x; As[r][kk + 1] = av.y;
            As[r][kk + 2] = av.z; As[r][kk + 3] = av.w;
        }
        {   // stage B tile 16x64
            const int kk = tid >> 4;
            const int n  = (tid & 15) * 4;
            const float4 bv = *reinterpret_cast<const float4*>(
                B + (size_t)(k0 + kk) * NHID + n0 + n);
            *reinterpret_cast<float4*>(&Bs[kk][n]) = bv;
        }
        __syncthreads();
#pragma unroll
        for (int kk = 0; kk < 16; ++kk) {
            const float a0 = As[ty * 4 + 0][kk];
            const float a1 = As[ty * 4 + 1][kk];
            const float a2 = As[ty * 4 + 2][kk];
            const float a3 = As[ty * 4 + 3][kk];
            const float4 b = *reinterpret_cast<const float4*>(&Bs[kk][tx * 4]);
            acc[0][0] += a0 * b.x; acc[0][1] += a0 * b.y; acc[0][2] += a0 * b.z; acc[0][3] += a0 * b.w;
            acc[1][0] += a1 * b.x; acc[1][1] += a1 * b.y; acc[1][2] += a1 * b.z; acc[1][3] += a1 * b.w;
            acc[2][0] += a2 * b.x; acc[2][1] += a2 * b.y; acc[2][2] += a2 * b.z; acc[2][3] += a2 * b.w;
            acc[3][0] += a3 * b.x; acc[3][1] += a3 * b.y; acc[3][2] += a3 * b.z; acc[3][3] += a3 * b.w;
        }
        __syncthreads();
    }
#pragma unroll
    for (int i = 0; i < 4; ++i) {
        float4 o = make_float4(acc[i][0], acc[i][1], acc[i][2], acc[i][3]);
        *reinterpret_cast<float4*>(
            rep_pre + (size_t)(by * 64 + ty * 4 + i) * 256 + bx * 64 + tx * 4) = o;
    }
}

// ============ K2: edge dedup pass 1 (bitmap ownership + row counts) =========
__global__ void edge_pass1(const int* __restrict__ ei, int E,
                           unsigned int* __restrict__ bitmap,
                           unsigned char* __restrict__ flag,
                           int* __restrict__ cnt)
{
    const int e = blockIdx.x * blockDim.x + threadIdx.x;
    if (e >= E) return;
    const int s = ei[e];
    const int d = ei[E + e];
    const unsigned int idx  = (unsigned int)s * 8192u + (unsigned int)d;
    const unsigned int mask = 1u << (idx & 31u);
    const unsigned int old  = atomicOr(&bitmap[idx >> 5], mask);
    const bool own = (old & mask) == 0u;
    flag[e] = own ? 1 : 0;
    if (own) atomicAdd(&cnt[s], 1);
}

// ============ K3: exclusive scan of cnt -> rowptr (single block) ============
__global__ __launch_bounds__(1024)
void scan_kernel(const int* __restrict__ cnt, int* __restrict__ rowptr)
{
    __shared__ int part[1024];
    const int tid = threadIdx.x;
    int loc[8];
    int s = 0;
#pragma unroll
    for (int j = 0; j < 8; ++j) { loc[j] = cnt[tid * 8 + j]; s += loc[j]; }
    part[tid] = s;
    __syncthreads();
    for (int off = 1; off < 1024; off <<= 1) {
        const int val = (tid >= off) ? part[tid - off] : 0;
        __syncthreads();
        part[tid] += val;
        __syncthreads();
    }
    int run = (tid == 0) ? 0 : part[tid - 1];
#pragma unroll
    for (int j = 0; j < 8; ++j) { rowptr[tid * 8 + j] = run; run += loc[j]; }
    if (tid == 1023) rowptr[8192] = run;
}

// ============ K4: edge dedup pass 2 (fill CSR columns) ======================
__global__ void edge_pass2(const int* __restrict__ ei, int E,
                           const unsigned char* __restrict__ flag,
                           const int* __restrict__ rowptr,
                           int* __restrict__ fill,
                           int* __restrict__ colidx)
{
    const int e = blockIdx.x * blockDim.x + threadIdx.x;
    if (e >= E) return;
    if (!flag[e]) return;
    const int s = ei[e];
    const int d = ei[E + e];
    const int pos = atomicAdd(&fill[s], 1);
    colidx[rowptr[s] + pos] = d;
}

// ============ K5: sort each row's columns (determinism) =====================
__global__ void sort_rows(const int* __restrict__ rowptr, int* __restrict__ colidx)
{
    const int i = blockIdx.x * blockDim.x + threadIdx.x;
    if (i >= N_NODES) return;
    const int rp = rowptr[i];
    const int n  = rowptr[i + 1] - rp;
    for (int a2 = 1; a2 < n; ++a2) {
        const int key = colidx[rp + a2];
        int b2 = a2 - 1;
        while (b2 >= 0 && colidx[rp + b2] > key) {
            colidx[rp + b2 + 1] = colidx[rp + b2];
            --b2;
        }
        colidx[rp + b2 + 1] = key;
    }
}

// ============ K6: CSR aggregate + bias + relu -> rep; u,v ===================
__global__ __launch_bounds__(256)
void aggregate_kernel(const float* __restrict__ rep_pre,
                      const int* __restrict__ rowptr,
                      const int* __restrict__ colidx,
                      const float* __restrict__ gcB,
                      const float* __restrict__ gctB,
                      const float* __restrict__ avec,
                      float* __restrict__ rep,
                      float* __restrict__ u,
                      float* __restrict__ v)
{
    const int i   = blockIdx.x;
    const int tid = threadIdx.x;
    const int rp  = rowptr[i];
    const int rpe = rowptr[i + 1];
    float acc = 0.f;
    for (int p = rp; p < rpe; ++p)
        acc += rep_pre[(size_t)colidx[p] * 256 + tid];
    const float bias = (tid < 128) ? gcB[tid] : gctB[tid - 128];
    const float val  = fmaxf(acc + bias, 0.f);
    rep[(size_t)i * 256 + tid] = val;

    __shared__ float su[256], sv[256];
    su[tid] = avec[tid] * val;
    sv[tid] = avec[256 + tid] * val;
    __syncthreads();
#pragma unroll
    for (int s = 128; s > 0; s >>= 1) {
        if (tid < s) { su[tid] += su[tid + s]; sv[tid] += sv[tid + s]; }
        __syncthreads();
    }
    if (tid == 0) { u[i] = su[0]; v[i] = sv[0]; }
}

// ============ K7: colsum of rep_t (deterministic two-stage) =================
__global__ __launch_bounds__(128)
void colsum_kernel(const float* __restrict__ rep, float* __restrict__ colpart)
{
    const int f = threadIdx.x;
    const int b = blockIdx.x;
    const int r0 = b * 128;
    float s = 0.f;
    for (int r = 0; r < 128; ++r)
        s += rep[(size_t)(r0 + r) * 256 + 128 + f];
    colpart[b * 128 + f] = s;
}

__global__ __launch_bounds__(128)
void colsum_final(const float* __restrict__ colpart, float* __restrict__ colsum)
{
    const int f = threadIdx.x;
    float s = 0.f;
    for (int b = 0; b < 64; ++b) s += colpart[b * 128 + f];
    colsum[f] = s;
}

// ============ K8: per-row attention + residual -> h_prime ===================
__global__ __launch_bounds__(128)
void attention_kernel(const int* __restrict__ rowptr,
                      const int* __restrict__ colidx,
                      const float* __restrict__ u,
                      const float* __restrict__ v,
                      const float* __restrict__ rep,
                      const float* __restrict__ colsum,
                      float* __restrict__ hp_out)
{
    const int i   = blockIdx.x;
    const int tid = threadIdx.x;
    const int rp  = rowptr[i];
    const int deg = rowptr[i + 1] - rp;
    const float ui = u[i];

    __shared__ float red[128];
    __shared__ float wsh[128];
    __shared__ int   csh[128];

    float mloc = -1e30f;
    for (int p = tid; p < deg; p += 128)
        mloc = fmaxf(mloc, ui + v[colidx[rp + p]]);
    red[tid] = mloc;
    __syncthreads();
#pragma unroll
    for (int s = 64; s > 0; s >>= 1) {
        if (tid < s) red[tid] = fmaxf(red[tid], red[tid + s]);
        __syncthreads();
    }
    const float m = fmaxf(red[0], 0.f);
    __syncthreads();
    const float e0 = expf(-m);

    float Zloc = 0.f;
    float acc  = 0.f;
    for (int base = 0; base < deg; base += 128) {
        const int p = base + tid;
        if (p < deg) {
            const int c = colidx[rp + p];
            csh[tid] = c;
            const float w = expf(ui + v[c] - m);
            wsh[tid] = w;
            Zloc += w;
        }
        __syncthreads();
        const int cnt2 = min(128, deg - base);
        for (int q = 0; q < cnt2; ++q)
            acc += (wsh[q] - e0) * rep[(size_t)csh[q] * 256 + 128 + tid];
        __syncthreads();
    }
    red[tid] = Zloc;
    __syncthreads();
#pragma unroll
    for (int s = 64; s > 0; s >>= 1) {
        if (tid < s) red[tid] += red[tid + s];
        __syncthreads();
    }
    const float Z  = red[0] + (8192.f - (float)deg) * e0;
    const float hv = (acc + e0 * colsum[tid]) / Z + rep[(size_t)i * 256 + tid];
    hp_out[(size_t)i * 128 + tid] = hv;
}

// ============ K9: output heads (treatment / y0 / y1 / select) ===============
__global__ __launch_bounds__(128)
void heads_kernel(const float* __restrict__ hprime,   // [N,128]
                  const float* __restrict__ rep,      // [N,256]
                  const int* __restrict__ t,
                  const float* __restrict__ ppW,  const float* __restrict__ ppB,
                  const float* __restrict__ pp2W, const float* __restrict__ pp2B,
                  const float* __restrict__ t00W, const float* __restrict__ t00B,
                  const float* __restrict__ t10W, const float* __restrict__ t10B,
                  const float* __restrict__ t01W, const float* __restrict__ t01B,
                  const float* __restrict__ t11W, const float* __restrict__ t11B,
                  float* __restrict__ y_out,
                  float* __restrict__ treat_out)
{
    const int f  = threadIdx.x;
    const int r0 = blockIdx.x * 8;
    __shared__ float hs[8][128];
    __shared__ float ts[8][128];
#pragma unroll
    for (int r = 0; r < 8; ++r) {
        hs[r][f] = hprime[(size_t)(r0 + r) * 128 + f];
        ts[r][f] = rep[(size_t)(r0 + r) * 256 + 128 + f];
    }
    __syncthreads();

    float a00[8], a10[8], app[8];
#pragma unroll
    for (int r = 0; r < 8; ++r) { a00[r] = 0.f; a10[r] = 0.f; app[r] = 0.f; }

    for (int k = 0; k < 128; ++k) {
        const float w00 = t00W[k * 128 + f];
        const float w10 = t10W[k * 128 + f];
        const float wpp = ppW [k * 128 + f];
#pragma unroll
        for (int r = 0; r < 8; ++r) {
            a00[r] += hs[r][k] * w00;
            a10[r] += hs[r][k] * w10;
            app[r] += ts[r][k] * wpp;
        }
    }
    __syncthreads();

    const float b00 = t00B[f], b10 = t10B[f], bpp = ppB[f];
    const float w01 = t01W[f], w11 = t11W[f];
    const float w20 = pp2W[2 * f + 0], w21 = pp2W[2 * f + 1];

    for (int r = 0; r < 8; ++r) {
        __syncthreads();
        const float h00 = fmaxf(a00[r] + b00, 0.f);
        const float h10 = fmaxf(a10[r] + b10, 0.f);
        const float hp2 = app[r] + bpp;
        hs[0][f] = h00 * w01;
        hs[1][f] = h10 * w11;
        hs[2][f] = hp2 * w20;
        hs[3][f] = hp2 * w21;
        __syncthreads();
#pragma unroll
        for (int s = 64; s > 0; s >>= 1) {
            if (f < s) {
                hs[0][f] += hs[0][f + s];
                hs[1][f] += hs[1][f + s];
                hs[2][f] += hs[2][f + s];
                hs[3][f] += hs[3][f + s];
            }
            __syncthreads();
        }
        if (f == 0) {
            const int node = r0 + r;
            const float y0 = hs[0][0] + t01B[0];
            const float y1 = hs[1][0] + t11B[0];
            y_out[node] = (t[node] > 0) ? y1 : y0;
            const float tr0 = hs[2][0] + pp2B[0];
            const float tr1 = hs[3][0] + pp2B[1];
            treat_out[node * 2 + 0] = 1.f / (1.f + expf(-tr0));
            treat_out[node * 2 + 1] = 1.f / (1.f + expf(-tr1));
        }
    }
}

// ===========================================================================
extern "C" void kernel_launch(void* const* d_in, const int* in_sizes, int n_in,
                              void* d_out, int out_size, void* d_ws, size_t ws_size,
                              hipStream_t stream)
{
    const float* x    = (const float*)d_in[0];
    // d_in[1] = dense adj : intentionally unused (structure rebuilt from edges)
    const int*   ei   = (const int*)d_in[2];
    const int*   t    = (const int*)d_in[3];
    const float* gcW  = (const float*)d_in[4];
    const float* gcB  = (const float*)d_in[5];
    const float* gctW = (const float*)d_in[6];
    const float* gctB = (const float*)d_in[7];
    const float* avec = (const float*)d_in[8];
    const float* ppW  = (const float*)d_in[9];
    const float* ppB  = (const float*)d_in[10];
    const float* pp2W = (const float*)d_in[11];
    const float* pp2B = (const float*)d_in[12];
    const float* t00W = (const float*)d_in[13];
    const float* t00B = (const float*)d_in[14];
    const float* t10W = (const float*)d_in[15];
    const float* t10B = (const float*)d_in[16];
    const float* t01W = (const float*)d_in[17];
    const float* t01B = (const float*)d_in[18];
    const float* t11W = (const float*)d_in[19];
    const float* t11B = (const float*)d_in[20];

    const int E = in_sizes[2] / 2;

    char* ws = (char*)d_ws;
    unsigned int*  bitmap  = (unsigned int*) (ws + 0);
    int*           cnt     = (int*)          (ws + 8388608);
    int*           fill    = (int*)          (ws + 8421376);
    float*         colsum  = (float*)        (ws + 8454144);
    const size_t   ZERO_BYTES = 8454656;
    float*         rep_pre = (float*)        (ws + 8454656);
    float*         rep     = (float*)        (ws + 16843264);
    float*         u       = (float*)        (ws + 25231872);
    float*         v       = (float*)        (ws + 25264640);
    int*           rowptr  = (int*)          (ws + 25297408);
    unsigned char* flag    = (unsigned char*)(ws + 25330432);
    int*           colidx  = (int*)          (ws + 25592576);
    float*         colpart = (float*)        (ws + 26641152);

    float* y_out  = (float*)d_out;
    float* hp_out = (float*)d_out + N_NODES;
    float* tr_out = (float*)d_out + N_NODES + (size_t)N_NODES * NHID;

    hipMemsetAsync(ws, 0, ZERO_BYTES, stream);

    gemm1_kernel<<<dim3(4, 128), 256, 0, stream>>>(x, gcW, gctW, rep_pre);
    edge_pass1<<<(E + 255) / 256, 256, 0, stream>>>(ei, E, bitmap, flag, cnt);
    scan_kernel<<<1, 1024, 0, stream>>>(cnt, rowptr);
    edge_pass2<<<(E + 255) / 256, 256, 0, stream>>>(ei, E, flag, rowptr, fill, colidx);
    sort_rows<<<32, 256, 0, stream>>>(rowptr, colidx);
    aggregate_kernel<<<N_NODES, 256, 0, stream>>>(rep_pre, rowptr, colidx,
                                                  gcB, gctB, avec, rep, u, v);
    colsum_kernel<<<64, 128, 0, stream>>>(rep, colpart);
    colsum_final<<<1, 128, 0, stream>>>(colpart, colsum);
    attention_kernel<<<N_NODES, 128, 0, stream>>>(rowptr, colidx, u, v, rep,
                                                  colsum, hp_out);
    heads_kernel<<<N_NODES / 8, 128, 0, stream>>>(hp_out, rep, t,
                                                  ppW, ppB, pp2W, pp2B,
                                                  t00W, t00B, t10W, t10B,
                                                  t01W, t01B, t11W, t11B,
                                                  y_out, tr_out);
}

// Round 2
// 218.531 us; speedup vs baseline: 2.1091x; 2.1091x over previous
//
#include <hip/hip_runtime.h>
#include <cstdint>
#include <cstddef>

#define N_NODES 8192
#define NFEAT   512
#define NHID    128

// ---------------------------------------------------------------------------
// Workspace layout (bytes):
//   [0]          bitmap   : 8192*8192/8 = 8388608   (zeroed each call)
//   [8388608]    cnt      : 8192*4      = 32768     (zeroed)
//   ZERO_BYTES = 8421376
//   [8421376]    rep_pre  : 8192*256*4  = 8388608
//   [16809984]   rep      : 8192*256*4  = 8388608
//   [25198592]   u        : 32768
//   [25231360]   v        : 32768
//   [25264128]   rowptr   : 33024 (pad to 33280)
//   [25297408]   colidx   : 262144*4 = 1048576
//   [26345984]   colpart  : 64*128*4 = 32768
//   [26378752]   colsum   : 512
//   end ~ 26.4 MB
// ---------------------------------------------------------------------------

// ============ K1: rep_pre = x @ [gc_W | gct_W]  (f32 tiled GEMM) ============
__global__ __launch_bounds__(256)
void gemm1_kernel(const float* __restrict__ x,
                  const float* __restrict__ gcW,
                  const float* __restrict__ gctW,
                  float* __restrict__ rep_pre)
{
    const int bx  = blockIdx.x;         // 0..3  (64-col blocks of 256)
    const int by  = blockIdx.y;         // 0..127 (64-row blocks of 8192)
    const int tid = threadIdx.x;
    const int tx  = tid & 15;
    const int ty  = tid >> 4;
    const float* B = (bx < 2) ? gcW : gctW;
    const int n0   = (bx & 1) * 64;

    __shared__ float As[64][17];
    __shared__ float Bs[16][64];

    float acc[4][4];
#pragma unroll
    for (int i = 0; i < 4; ++i)
#pragma unroll
        for (int j = 0; j < 4; ++j) acc[i][j] = 0.f;

    for (int kb = 0; kb < NFEAT / 16; ++kb) {
        const int k0 = kb * 16;
        {   // stage A tile 64x16 (one float4 per thread)
            const int r  = tid >> 2;
            const int kk = (tid & 3) * 4;
            const float4 av = *reinterpret_cast<const float4*>(
                x + (size_t)(by * 64 + r) * NFEAT + k0 + kk);
            As[r][kk + 0] = av.x; As[r][kk + 1] = av.y;
            As[r][kk + 2] = av.z; As[r][kk + 3] = av.w;
        }
        {   // stage B tile 16x64
            const int kk = tid >> 4;
            const int n  = (tid & 15) * 4;
            const float4 bv = *reinterpret_cast<const float4*>(
                B + (size_t)(k0 + kk) * NHID + n0 + n);
            *reinterpret_cast<float4*>(&Bs[kk][n]) = bv;
        }
        __syncthreads();
#pragma unroll
        for (int kk = 0; kk < 16; ++kk) {
            const float a0 = As[ty * 4 + 0][kk];
            const float a1 = As[ty * 4 + 1][kk];
            const float a2 = As[ty * 4 + 2][kk];
            const float a3 = As[ty * 4 + 3][kk];
            const float4 b = *reinterpret_cast<const float4*>(&Bs[kk][tx * 4]);
            acc[0][0] += a0 * b.x; acc[0][1] += a0 * b.y; acc[0][2] += a0 * b.z; acc[0][3] += a0 * b.w;
            acc[1][0] += a1 * b.x; acc[1][1] += a1 * b.y; acc[1][2] += a1 * b.z; acc[1][3] += a1 * b.w;
            acc[2][0] += a2 * b.x; acc[2][1] += a2 * b.y; acc[2][2] += a2 * b.z; acc[2][3] += a2 * b.w;
            acc[3][0] += a3 * b.x; acc[3][1] += a3 * b.y; acc[3][2] += a3 * b.z; acc[3][3] += a3 * b.w;
        }
        __syncthreads();
    }
#pragma unroll
    for (int i = 0; i < 4; ++i) {
        float4 o = make_float4(acc[i][0], acc[i][1], acc[i][2], acc[i][3]);
        *reinterpret_cast<float4*>(
            rep_pre + (size_t)(by * 64 + ty * 4 + i) * 256 + bx * 64 + tx * 4) = o;
    }
}

// ============ K2: edge dedup (bitmap ownership + row counts) ================
__global__ void edge_pass1(const int* __restrict__ ei, int E,
                           unsigned int* __restrict__ bitmap,
                           int* __restrict__ cnt)
{
    const int e = blockIdx.x * blockDim.x + threadIdx.x;
    if (e >= E) return;
    const int s = ei[e];
    const int d = ei[E + e];
    const unsigned int idx  = (unsigned int)s * 8192u + (unsigned int)d;
    const unsigned int mask = 1u << (idx & 31u);
    const unsigned int old  = atomicOr(&bitmap[idx >> 5], mask);
    if ((old & mask) == 0u) atomicAdd(&cnt[s], 1);  // int add: deterministic
}

// ============ K3: exclusive scan of cnt -> rowptr (single block) ============
__global__ __launch_bounds__(1024)
void scan_kernel(const int* __restrict__ cnt, int* __restrict__ rowptr)
{
    __shared__ int part[1024];
    const int tid = threadIdx.x;
    int loc[8];
    int s = 0;
#pragma unroll
    for (int j = 0; j < 8; ++j) { loc[j] = cnt[tid * 8 + j]; s += loc[j]; }
    part[tid] = s;
    __syncthreads();
    for (int off = 1; off < 1024; off <<= 1) {
        const int val = (tid >= off) ? part[tid - off] : 0;
        __syncthreads();
        part[tid] += val;
        __syncthreads();
    }
    int run = (tid == 0) ? 0 : part[tid - 1];
#pragma unroll
    for (int j = 0; j < 8; ++j) { rowptr[tid * 8 + j] = run; run += loc[j]; }
    if (tid == 1023) rowptr[8192] = run;
}

// ============ K4: extract sorted columns straight from the bitmap ===========
// One wave per row. Lane l owns words [4l, 4l+4) of the row's 256 bitmap
// words; bits emitted in word/bit order -> colidx sorted ascending. No
// atomics, fully deterministic.
__global__ __launch_bounds__(64)
void bitmap_extract(const unsigned int* __restrict__ bitmap,
                    const int* __restrict__ rowptr,
                    int* __restrict__ colidx)
{
    const int row  = blockIdx.x;
    const int lane = threadIdx.x;
    const uint4 w = *reinterpret_cast<const uint4*>(
        bitmap + (size_t)row * 256 + lane * 4);
    const int c = __popc(w.x) + __popc(w.y) + __popc(w.z) + __popc(w.w);
    // inclusive scan over 64 lanes, then make exclusive
    int off = c;
    for (int d = 1; d < 64; d <<= 1) {
        const int n = __shfl_up(off, d, 64);
        if (lane >= d) off += n;
    }
    off -= c;
    int pos = rowptr[row] + off;
    const int base = lane * 128;
    unsigned int wv[4] = {w.x, w.y, w.z, w.w};
#pragma unroll
    for (int j = 0; j < 4; ++j) {
        unsigned int b = wv[j];
        while (b) {
            const int bit = __ffs(b) - 1;
            colidx[pos++] = base + j * 32 + bit;
            b &= b - 1;
        }
    }
}

// ============ K5: CSR aggregate + bias + relu -> rep; u,v ===================
__global__ __launch_bounds__(256)
void aggregate_kernel(const float* __restrict__ rep_pre,
                      const int* __restrict__ rowptr,
                      const int* __restrict__ colidx,
                      const float* __restrict__ gcB,
                      const float* __restrict__ gctB,
                      const float* __restrict__ avec,
                      float* __restrict__ rep,
                      float* __restrict__ u,
                      float* __restrict__ v)
{
    const int i   = blockIdx.x;
    const int tid = threadIdx.x;
    const int rp  = rowptr[i];
    const int rpe = rowptr[i + 1];
    float acc = 0.f;
    for (int p = rp; p < rpe; ++p)
        acc += rep_pre[(size_t)colidx[p] * 256 + tid];
    const float bias = (tid < 128) ? gcB[tid] : gctB[tid - 128];
    const float val  = fmaxf(acc + bias, 0.f);
    rep[(size_t)i * 256 + tid] = val;

    __shared__ float su[256], sv[256];
    su[tid] = avec[tid] * val;
    sv[tid] = avec[256 + tid] * val;
    __syncthreads();
#pragma unroll
    for (int s = 128; s > 0; s >>= 1) {
        if (tid < s) { su[tid] += su[tid + s]; sv[tid] += sv[tid + s]; }
        __syncthreads();
    }
    if (tid == 0) { u[i] = su[0]; v[i] = sv[0]; }
}

// ============ K6: colsum of rep_t (deterministic two-stage) =================
__global__ __launch_bounds__(128)
void colsum_kernel(const float* __restrict__ rep, float* __restrict__ colpart)
{
    const int f = threadIdx.x;
    const int b = blockIdx.x;
    const int r0 = b * 128;
    float s = 0.f;
    for (int r = 0; r < 128; ++r)
        s += rep[(size_t)(r0 + r) * 256 + 128 + f];
    colpart[b * 128 + f] = s;
}

__global__ __launch_bounds__(128)
void colsum_final(const float* __restrict__ colpart, float* __restrict__ colsum)
{
    const int f = threadIdx.x;
    float s = 0.f;
    for (int b = 0; b < 64; ++b) s += colpart[b * 128 + f];
    colsum[f] = s;
}

// ============ K7: per-row attention + residual -> h_prime ===================
__global__ __launch_bounds__(128)
void attention_kernel(const int* __restrict__ rowptr,
                      const int* __restrict__ colidx,
                      const float* __restrict__ u,
                      const float* __restrict__ v,
                      const float* __restrict__ rep,
                      const float* __restrict__ colsum,
                      float* __restrict__ hp_out)
{
    const int i   = blockIdx.x;
    const int tid = threadIdx.x;
    const int rp  = rowptr[i];
    const int deg = rowptr[i + 1] - rp;
    const float ui = u[i];

    __shared__ float red[128];
    __shared__ float wsh[128];
    __shared__ int   csh[128];

    float mloc = -1e30f;
    for (int p = tid; p < deg; p += 128)
        mloc = fmaxf(mloc, ui + v[colidx[rp + p]]);
    red[tid] = mloc;
    __syncthreads();
#pragma unroll
    for (int s = 64; s > 0; s >>= 1) {
        if (tid < s) red[tid] = fmaxf(red[tid], red[tid + s]);
        __syncthreads();
    }
    const float m = fmaxf(red[0], 0.f);
    __syncthreads();
    const float e0 = expf(-m);

    float Zloc = 0.f;
    float acc  = 0.f;
    for (int base = 0; base < deg; base += 128) {
        const int p = base + tid;
        if (p < deg) {
            const int c = colidx[rp + p];
            csh[tid] = c;
            const float w = expf(ui + v[c] - m);
            wsh[tid] = w;
            Zloc += w;
        }
        __syncthreads();
        const int cnt2 = min(128, deg - base);
        for (int q = 0; q < cnt2; ++q)
            acc += (wsh[q] - e0) * rep[(size_t)csh[q] * 256 + 128 + tid];
        __syncthreads();
    }
    red[tid] = Zloc;
    __syncthreads();
#pragma unroll
    for (int s = 64; s > 0; s >>= 1) {
        if (tid < s) red[tid] += red[tid + s];
        __syncthreads();
    }
    const float Z  = red[0] + (8192.f - (float)deg) * e0;
    const float hv = (acc + e0 * colsum[tid]) / Z + rep[(size_t)i * 256 + tid];
    hp_out[(size_t)i * 128 + tid] = hv;
}

// ============ K8: output heads (treatment / y0 / y1 / select) ===============
__global__ __launch_bounds__(128)
void heads_kernel(const float* __restrict__ hprime,   // [N,128]
                  const float* __restrict__ rep,      // [N,256]
                  const int* __restrict__ t,
                  const float* __restrict__ ppW,  const float* __restrict__ ppB,
                  const float* __restrict__ pp2W, const float* __restrict__ pp2B,
                  const float* __restrict__ t00W, const float* __restrict__ t00B,
                  const float* __restrict__ t10W, const float* __restrict__ t10B,
                  const float* __restrict__ t01W, const float* __restrict__ t01B,
                  const float* __restrict__ t11W, const float* __restrict__ t11B,
                  float* __restrict__ y_out,
                  float* __restrict__ treat_out)
{
    const int f  = threadIdx.x;
    const int r0 = blockIdx.x * 8;
    __shared__ float hs[8][128];
    __shared__ float ts[8][128];
#pragma unroll
    for (int r = 0; r < 8; ++r) {
        hs[r][f] = hprime[(size_t)(r0 + r) * 128 + f];
        ts[r][f] = rep[(size_t)(r0 + r) * 256 + 128 + f];
    }
    __syncthreads();

    float a00[8], a10[8], app[8];
#pragma unroll
    for (int r = 0; r < 8; ++r) { a00[r] = 0.f; a10[r] = 0.f; app[r] = 0.f; }

    for (int k = 0; k < 128; ++k) {
        const float w00 = t00W[k * 128 + f];
        const float w10 = t10W[k * 128 + f];
        const float wpp = ppW [k * 128 + f];
#pragma unroll
        for (int r = 0; r < 8; ++r) {
            a00[r] += hs[r][k] * w00;
            a10[r] += hs[r][k] * w10;
            app[r] += ts[r][k] * wpp;
        }
    }
    __syncthreads();

    const float b00 = t00B[f], b10 = t10B[f], bpp = ppB[f];
    const float w01 = t01W[f], w11 = t11W[f];
    const float w20 = pp2W[2 * f + 0], w21 = pp2W[2 * f + 1];

    for (int r = 0; r < 8; ++r) {
        __syncthreads();
        const float h00 = fmaxf(a00[r] + b00, 0.f);
        const float h10 = fmaxf(a10[r] + b10, 0.f);
        const float hp2 = app[r] + bpp;
        hs[0][f] = h00 * w01;
        hs[1][f] = h10 * w11;
        hs[2][f] = hp2 * w20;
        hs[3][f] = hp2 * w21;
        __syncthreads();
#pragma unroll
        for (int s = 64; s > 0; s >>= 1) {
            if (f < s) {
                hs[0][f] += hs[0][f + s];
                hs[1][f] += hs[1][f + s];
                hs[2][f] += hs[2][f + s];
                hs[3][f] += hs[3][f + s];
            }
            __syncthreads();
        }
        if (f == 0) {
            const int node = r0 + r;
            const float y0 = hs[0][0] + t01B[0];
            const float y1 = hs[1][0] + t11B[0];
            y_out[node] = (t[node] > 0) ? y1 : y0;
            const float tr0 = hs[2][0] + pp2B[0];
            const float tr1 = hs[3][0] + pp2B[1];
            treat_out[node * 2 + 0] = 1.f / (1.f + expf(-tr0));
            treat_out[node * 2 + 1] = 1.f / (1.f + expf(-tr1));
        }
    }
}

// ===========================================================================
extern "C" void kernel_launch(void* const* d_in, const int* in_sizes, int n_in,
                              void* d_out, int out_size, void* d_ws, size_t ws_size,
                              hipStream_t stream)
{
    const float* x    = (const float*)d_in[0];
    // d_in[1] = dense adj : intentionally unused (structure rebuilt from edges)
    const int*   ei   = (const int*)d_in[2];
    const int*   t    = (const int*)d_in[3];
    const float* gcW  = (const float*)d_in[4];
    const float* gcB  = (const float*)d_in[5];
    const float* gctW = (const float*)d_in[6];
    const float* gctB = (const float*)d_in[7];
    const float* avec = (const float*)d_in[8];
    const float* ppW  = (const float*)d_in[9];
    const float* ppB  = (const float*)d_in[10];
    const float* pp2W = (const float*)d_in[11];
    const float* pp2B = (const float*)d_in[12];
    const float* t00W = (const float*)d_in[13];
    const float* t00B = (const float*)d_in[14];
    const float* t10W = (const float*)d_in[15];
    const float* t10B = (const float*)d_in[16];
    const float* t01W = (const float*)d_in[17];
    const float* t01B = (const float*)d_in[18];
    const float* t11W = (const float*)d_in[19];
    const float* t11B = (const float*)d_in[20];

    const int E = in_sizes[2] / 2;

    char* ws = (char*)d_ws;
    unsigned int*  bitmap  = (unsigned int*) (ws + 0);
    int*           cnt     = (int*)          (ws + 8388608);
    const size_t   ZERO_BYTES = 8421376;
    float*         rep_pre = (float*)        (ws + 8421376);
    float*         rep     = (float*)        (ws + 16809984);
    float*         u       = (float*)        (ws + 25198592);
    float*         v       = (float*)        (ws + 25231360);
    int*           rowptr  = (int*)          (ws + 25264128);
    int*           colidx  = (int*)          (ws + 25297408);
    float*         colpart = (float*)        (ws + 26345984);
    float*         colsum  = (float*)        (ws + 26378752);

    float* y_out  = (float*)d_out;
    float* hp_out = (float*)d_out + N_NODES;
    float* tr_out = (float*)d_out + N_NODES + (size_t)N_NODES * NHID;

    hipMemsetAsync(ws, 0, ZERO_BYTES, stream);

    gemm1_kernel<<<dim3(4, 128), 256, 0, stream>>>(x, gcW, gctW, rep_pre);
    edge_pass1<<<(E + 255) / 256, 256, 0, stream>>>(ei, E, bitmap, cnt);
    scan_kernel<<<1, 1024, 0, stream>>>(cnt, rowptr);
    bitmap_extract<<<N_NODES, 64, 0, stream>>>(bitmap, rowptr, colidx);
    aggregate_kernel<<<N_NODES, 256, 0, stream>>>(rep_pre, rowptr, colidx,
                                                  gcB, gctB, avec, rep, u, v);
    colsum_kernel<<<64, 128, 0, stream>>>(rep, colpart);
    colsum_final<<<1, 128, 0, stream>>>(colpart, colsum);
    attention_kernel<<<N_NODES, 128, 0, stream>>>(rowptr, colidx, u, v, rep,
                                                  colsum, hp_out);
    heads_kernel<<<N_NODES / 8, 128, 0, stream>>>(hp_out, rep, t,
                                                  ppW, ppB, pp2W, pp2B,
                                                  t00W, t00B, t10W, t10B,
                                                  t01W, t01B, t11W, t11B,
                                                  y_out, tr_out);
}

// Round 3
// 218.345 us; speedup vs baseline: 2.1109x; 1.0009x over previous
//
#include <hip/hip_runtime.h>
#include <cstdint>
#include <cstddef>

#define N_NODES 8192
#define NFEAT   512
#define NHID    128

// ---------------------------------------------------------------------------
// Workspace layout (bytes):
//   [0]          bitmap   : 8192*8192/8 = 8388608   (zeroed each call by zero_ws)
//   [8388608]    cnt      : 8192*4      = 32768     (zeroed)
//   ZERO_BYTES = 8421376  (= 526336 uint4)
//   [8421376]    rep_pre  : 8192*256*4  = 8388608
//   [16809984]   rep      : 8192*256*4  = 8388608
//   [25198592]   u        : 32768
//   [25231360]   v        : 32768
//   [25264128]   rowptr   : 33024 (pad to 33280)
//   [25297408]   colidx   : 262144*4 = 1048576
//   [26345984]   colpart  : 64*128*4 = 32768
//   [26378752]   colsum   : 512
//   end ~ 26.4 MB
// ---------------------------------------------------------------------------

// ============ K0: zero bitmap+cnt (runtime fill kernel is ~53 GB/s — ours
//               does uint4 grid-stride at HBM rate) ==========================
__global__ __launch_bounds__(256)
void zero_ws(uint4* __restrict__ p, int n16)
{
    const uint4 z = make_uint4(0u, 0u, 0u, 0u);
    for (int i = blockIdx.x * blockDim.x + threadIdx.x; i < n16;
         i += gridDim.x * blockDim.x)
        p[i] = z;
}

// ============ K1: rep_pre = x @ [gc_W | gct_W]  (f32 tiled GEMM) ============
__global__ __launch_bounds__(256)
void gemm1_kernel(const float* __restrict__ x,
                  const float* __restrict__ gcW,
                  const float* __restrict__ gctW,
                  float* __restrict__ rep_pre)
{
    const int bx  = blockIdx.x;         // 0..3  (64-col blocks of 256)
    const int by  = blockIdx.y;         // 0..127 (64-row blocks of 8192)
    const int tid = threadIdx.x;
    const int tx  = tid & 15;
    const int ty  = tid >> 4;
    const float* B = (bx < 2) ? gcW : gctW;
    const int n0   = (bx & 1) * 64;

    __shared__ float As[64][17];
    __shared__ float Bs[16][64];

    float acc[4][4];
#pragma unroll
    for (int i = 0; i < 4; ++i)
#pragma unroll
        for (int j = 0; j < 4; ++j) acc[i][j] = 0.f;

    for (int kb = 0; kb < NFEAT / 16; ++kb) {
        const int k0 = kb * 16;
        {   // stage A tile 64x16 (one float4 per thread)
            const int r  = tid >> 2;
            const int kk = (tid & 3) * 4;
            const float4 av = *reinterpret_cast<const float4*>(
                x + (size_t)(by * 64 + r) * NFEAT + k0 + kk);
            As[r][kk + 0] = av.x; As[r][kk + 1] = av.y;
            As[r][kk + 2] = av.z; As[r][kk + 3] = av.w;
        }
        {   // stage B tile 16x64
            const int kk = tid >> 4;
            const int n  = (tid & 15) * 4;
            const float4 bv = *reinterpret_cast<const float4*>(
                B + (size_t)(k0 + kk) * NHID + n0 + n);
            *reinterpret_cast<float4*>(&Bs[kk][n]) = bv;
        }
        __syncthreads();
#pragma unroll
        for (int kk = 0; kk < 16; ++kk) {
            const float a0 = As[ty * 4 + 0][kk];
            const float a1 = As[ty * 4 + 1][kk];
            const float a2 = As[ty * 4 + 2][kk];
            const float a3 = As[ty * 4 + 3][kk];
            const float4 b = *reinterpret_cast<const float4*>(&Bs[kk][tx * 4]);
            acc[0][0] += a0 * b.x; acc[0][1] += a0 * b.y; acc[0][2] += a0 * b.z; acc[0][3] += a0 * b.w;
            acc[1][0] += a1 * b.x; acc[1][1] += a1 * b.y; acc[1][2] += a1 * b.z; acc[1][3] += a1 * b.w;
            acc[2][0] += a2 * b.x; acc[2][1] += a2 * b.y; acc[2][2] += a2 * b.z; acc[2][3] += a2 * b.w;
            acc[3][0] += a3 * b.x; acc[3][1] += a3 * b.y; acc[3][2] += a3 * b.z; acc[3][3] += a3 * b.w;
        }
        __syncthreads();
    }
#pragma unroll
    for (int i = 0; i < 4; ++i) {
        float4 o = make_float4(acc[i][0], acc[i][1], acc[i][2], acc[i][3]);
        *reinterpret_cast<float4*>(
            rep_pre + (size_t)(by * 64 + ty * 4 + i) * 256 + bx * 64 + tx * 4) = o;
    }
}

// ============ K2: edge dedup (bitmap ownership + row counts) ================
__global__ void edge_pass1(const int* __restrict__ ei, int E,
                           unsigned int* __restrict__ bitmap,
                           int* __restrict__ cnt)
{
    const int e = blockIdx.x * blockDim.x + threadIdx.x;
    if (e >= E) return;
    const int s = ei[e];
    const int d = ei[E + e];
    const unsigned int idx  = (unsigned int)s * 8192u + (unsigned int)d;
    const unsigned int mask = 1u << (idx & 31u);
    const unsigned int old  = atomicOr(&bitmap[idx >> 5], mask);
    if ((old & mask) == 0u) atomicAdd(&cnt[s], 1);  // int add: deterministic
}

// ============ K3: exclusive scan of cnt -> rowptr (single block) ============
__global__ __launch_bounds__(1024)
void scan_kernel(const int* __restrict__ cnt, int* __restrict__ rowptr)
{
    __shared__ int part[1024];
    const int tid = threadIdx.x;
    int loc[8];
    int s = 0;
#pragma unroll
    for (int j = 0; j < 8; ++j) { loc[j] = cnt[tid * 8 + j]; s += loc[j]; }
    part[tid] = s;
    __syncthreads();
    for (int off = 1; off < 1024; off <<= 1) {
        const int val = (tid >= off) ? part[tid - off] : 0;
        __syncthreads();
        part[tid] += val;
        __syncthreads();
    }
    int run = (tid == 0) ? 0 : part[tid - 1];
#pragma unroll
    for (int j = 0; j < 8; ++j) { rowptr[tid * 8 + j] = run; run += loc[j]; }
    if (tid == 1023) rowptr[8192] = run;
}

// ============ K4: extract sorted columns straight from the bitmap ===========
// One wave per row. Lane l owns words [4l, 4l+4) of the row's 256 bitmap
// words; bits emitted in word/bit order -> colidx sorted ascending. No
// atomics, fully deterministic.
__global__ __launch_bounds__(64)
void bitmap_extract(const unsigned int* __restrict__ bitmap,
                    const int* __restrict__ rowptr,
                    int* __restrict__ colidx)
{
    const int row  = blockIdx.x;
    const int lane = threadIdx.x;
    const uint4 w = *reinterpret_cast<const uint4*>(
        bitmap + (size_t)row * 256 + lane * 4);
    const int c = __popc(w.x) + __popc(w.y) + __popc(w.z) + __popc(w.w);
    // inclusive scan over 64 lanes, then make exclusive
    int off = c;
    for (int d = 1; d < 64; d <<= 1) {
        const int n = __shfl_up(off, d, 64);
        if (lane >= d) off += n;
    }
    off -= c;
    int pos = rowptr[row] + off;
    const int base = lane * 128;
    unsigned int wv[4] = {w.x, w.y, w.z, w.w};
#pragma unroll
    for (int j = 0; j < 4; ++j) {
        unsigned int b = wv[j];
        while (b) {
            const int bit = __ffs(b) - 1;
            colidx[pos++] = base + j * 32 + bit;
            b &= b - 1;
        }
    }
}

// ============ K5: CSR aggregate + bias + relu -> rep; u,v ===================
__global__ __launch_bounds__(256)
void aggregate_kernel(const float* __restrict__ rep_pre,
                      const int* __restrict__ rowptr,
                      const int* __restrict__ colidx,
                      const float* __restrict__ gcB,
                      const float* __restrict__ gctB,
                      const float* __restrict__ avec,
                      float* __restrict__ rep,
                      float* __restrict__ u,
                      float* __restrict__ v)
{
    const int i   = blockIdx.x;
    const int tid = threadIdx.x;
    const int rp  = rowptr[i];
    const int rpe = rowptr[i + 1];
    float acc = 0.f;
    for (int p = rp; p < rpe; ++p)
        acc += rep_pre[(size_t)colidx[p] * 256 + tid];
    const float bias = (tid < 128) ? gcB[tid] : gctB[tid - 128];
    const float val  = fmaxf(acc + bias, 0.f);
    rep[(size_t)i * 256 + tid] = val;

    __shared__ float su[256], sv[256];
    su[tid] = avec[tid] * val;
    sv[tid] = avec[256 + tid] * val;
    __syncthreads();
#pragma unroll
    for (int s = 128; s > 0; s >>= 1) {
        if (tid < s) { su[tid] += su[tid + s]; sv[tid] += sv[tid + s]; }
        __syncthreads();
    }
    if (tid == 0) { u[i] = su[0]; v[i] = sv[0]; }
}

// ============ K6: colsum of rep_t (deterministic two-stage) =================
__global__ __launch_bounds__(128)
void colsum_kernel(const float* __restrict__ rep, float* __restrict__ colpart)
{
    const int f = threadIdx.x;
    const int b = blockIdx.x;
    const int r0 = b * 128;
    float s = 0.f;
    for (int r = 0; r < 128; ++r)
        s += rep[(size_t)(r0 + r) * 256 + 128 + f];
    colpart[b * 128 + f] = s;
}

__global__ __launch_bounds__(128)
void colsum_final(const float* __restrict__ colpart, float* __restrict__ colsum)
{
    const int f = threadIdx.x;
    float s = 0.f;
    for (int b = 0; b < 64; ++b) s += colpart[b * 128 + f];
    colsum[f] = s;
}

// ============ K7: per-row attention + residual -> h_prime ===================
__global__ __launch_bounds__(128)
void attention_kernel(const int* __restrict__ rowptr,
                      const int* __restrict__ colidx,
                      const float* __restrict__ u,
                      const float* __restrict__ v,
                      const float* __restrict__ rep,
                      const float* __restrict__ colsum,
                      float* __restrict__ hp_out)
{
    const int i   = blockIdx.x;
    const int tid = threadIdx.x;
    const int rp  = rowptr[i];
    const int deg = rowptr[i + 1] - rp;
    const float ui = u[i];

    __shared__ float red[128];
    __shared__ float wsh[128];
    __shared__ int   csh[128];

    float mloc = -1e30f;
    for (int p = tid; p < deg; p += 128)
        mloc = fmaxf(mloc, ui + v[colidx[rp + p]]);
    red[tid] = mloc;
    __syncthreads();
#pragma unroll
    for (int s = 64; s > 0; s >>= 1) {
        if (tid < s) red[tid] = fmaxf(red[tid], red[tid + s]);
        __syncthreads();
    }
    const float m = fmaxf(red[0], 0.f);
    __syncthreads();
    const float e0 = expf(-m);

    float Zloc = 0.f;
    float acc  = 0.f;
    for (int base = 0; base < deg; base += 128) {
        const int p = base + tid;
        if (p < deg) {
            const int c = colidx[rp + p];
            csh[tid] = c;
            const float w = expf(ui + v[c] - m);
            wsh[tid] = w;
            Zloc += w;
        }
        __syncthreads();
        const int cnt2 = min(128, deg - base);
        for (int q = 0; q < cnt2; ++q)
            acc += (wsh[q] - e0) * rep[(size_t)csh[q] * 256 + 128 + tid];
        __syncthreads();
    }
    red[tid] = Zloc;
    __syncthreads();
#pragma unroll
    for (int s = 64; s > 0; s >>= 1) {
        if (tid < s) red[tid] += red[tid + s];
        __syncthreads();
    }
    const float Z  = red[0] + (8192.f - (float)deg) * e0;
    const float hv = (acc + e0 * colsum[tid]) / Z + rep[(size_t)i * 256 + tid];
    hp_out[(size_t)i * 128 + tid] = hv;
}

// ============ K8: output heads (treatment / y0 / y1 / select) ===============
__global__ __launch_bounds__(128)
void heads_kernel(const float* __restrict__ hprime,   // [N,128]
                  const float* __restrict__ rep,      // [N,256]
                  const int* __restrict__ t,
                  const float* __restrict__ ppW,  const float* __restrict__ ppB,
                  const float* __restrict__ pp2W, const float* __restrict__ pp2B,
                  const float* __restrict__ t00W, const float* __restrict__ t00B,
                  const float* __restrict__ t10W, const float* __restrict__ t10B,
                  const float* __restrict__ t01W, const float* __restrict__ t01B,
                  const float* __restrict__ t11W, const float* __restrict__ t11B,
                  float* __restrict__ y_out,
                  float* __restrict__ treat_out)
{
    const int f  = threadIdx.x;
    const int r0 = blockIdx.x * 8;
    __shared__ float hs[8][128];
    __shared__ float ts[8][128];
#pragma unroll
    for (int r = 0; r < 8; ++r) {
        hs[r][f] = hprime[(size_t)(r0 + r) * 128 + f];
        ts[r][f] = rep[(size_t)(r0 + r) * 256 + 128 + f];
    }
    __syncthreads();

    float a00[8], a10[8], app[8];
#pragma unroll
    for (int r = 0; r < 8; ++r) { a00[r] = 0.f; a10[r] = 0.f; app[r] = 0.f; }

    for (int k = 0; k < 128; ++k) {
        const float w00 = t00W[k * 128 + f];
        const float w10 = t10W[k * 128 + f];
        const float wpp = ppW [k * 128 + f];
#pragma unroll
        for (int r = 0; r < 8; ++r) {
            a00[r] += hs[r][k] * w00;
            a10[r] += hs[r][k] * w10;
            app[r] += ts[r][k] * wpp;
        }
    }
    __syncthreads();

    const float b00 = t00B[f], b10 = t10B[f], bpp = ppB[f];
    const float w01 = t01W[f], w11 = t11W[f];
    const float w20 = pp2W[2 * f + 0], w21 = pp2W[2 * f + 1];

    for (int r = 0; r < 8; ++r) {
        __syncthreads();
        const float h00 = fmaxf(a00[r] + b00, 0.f);
        const float h10 = fmaxf(a10[r] + b10, 0.f);
        const float hp2 = app[r] + bpp;
        hs[0][f] = h00 * w01;
        hs[1][f] = h10 * w11;
        hs[2][f] = hp2 * w20;
        hs[3][f] = hp2 * w21;
        __syncthreads();
#pragma unroll
        for (int s = 64; s > 0; s >>= 1) {
            if (f < s) {
                hs[0][f] += hs[0][f + s];
                hs[1][f] += hs[1][f + s];
                hs[2][f] += hs[2][f + s];
                hs[3][f] += hs[3][f + s];
            }
            __syncthreads();
        }
        if (f == 0) {
            const int node = r0 + r;
            const float y0 = hs[0][0] + t01B[0];
            const float y1 = hs[1][0] + t11B[0];
            y_out[node] = (t[node] > 0) ? y1 : y0;
            const float tr0 = hs[2][0] + pp2B[0];
            const float tr1 = hs[3][0] + pp2B[1];
            treat_out[node * 2 + 0] = 1.f / (1.f + expf(-tr0));
            treat_out[node * 2 + 1] = 1.f / (1.f + expf(-tr1));
        }
    }
}

// ===========================================================================
extern "C" void kernel_launch(void* const* d_in, const int* in_sizes, int n_in,
                              void* d_out, int out_size, void* d_ws, size_t ws_size,
                              hipStream_t stream)
{
    const float* x    = (const float*)d_in[0];
    // d_in[1] = dense adj : intentionally unused (structure rebuilt from edges)
    const int*   ei   = (const int*)d_in[2];
    const int*   t    = (const int*)d_in[3];
    const float* gcW  = (const float*)d_in[4];
    const float* gcB  = (const float*)d_in[5];
    const float* gctW = (const float*)d_in[6];
    const float* gctB = (const float*)d_in[7];
    const float* avec = (const float*)d_in[8];
    const float* ppW  = (const float*)d_in[9];
    const float* ppB  = (const float*)d_in[10];
    const float* pp2W = (const float*)d_in[11];
    const float* pp2B = (const float*)d_in[12];
    const float* t00W = (const float*)d_in[13];
    const float* t00B = (const float*)d_in[14];
    const float* t10W = (const float*)d_in[15];
    const float* t10B = (const float*)d_in[16];
    const float* t01W = (const float*)d_in[17];
    const float* t01B = (const float*)d_in[18];
    const float* t11W = (const float*)d_in[19];
    const float* t11B = (const float*)d_in[20];

    const int E = in_sizes[2] / 2;

    char* ws = (char*)d_ws;
    unsigned int*  bitmap  = (unsigned int*) (ws + 0);
    int*           cnt     = (int*)          (ws + 8388608);
    const size_t   ZERO_BYTES = 8421376;    // bitmap + cnt, 16B-multiple
    float*         rep_pre = (float*)        (ws + 8421376);
    float*         rep     = (float*)        (ws + 16809984);
    float*         u       = (float*)        (ws + 25198592);
    float*         v       = (float*)        (ws + 25231360);
    int*           rowptr  = (int*)          (ws + 25264128);
    int*           colidx  = (int*)          (ws + 25297408);
    float*         colpart = (float*)        (ws + 26345984);
    float*         colsum  = (float*)        (ws + 26378752);

    float* y_out  = (float*)d_out;
    float* hp_out = (float*)d_out + N_NODES;
    float* tr_out = (float*)d_out + N_NODES + (size_t)N_NODES * NHID;

    // zero bitmap+cnt with our own vectorized fill (runtime memset ~53 GB/s)
    zero_ws<<<2048, 256, 0, stream>>>((uint4*)ws, (int)(ZERO_BYTES / 16));

    gemm1_kernel<<<dim3(4, 128), 256, 0, stream>>>(x, gcW, gctW, rep_pre);
    edge_pass1<<<(E + 255) / 256, 256, 0, stream>>>(ei, E, bitmap, cnt);
    scan_kernel<<<1, 1024, 0, stream>>>(cnt, rowptr);
    bitmap_extract<<<N_NODES, 64, 0, stream>>>(bitmap, rowptr, colidx);
    aggregate_kernel<<<N_NODES, 256, 0, stream>>>(rep_pre, rowptr, colidx,
                                                  gcB, gctB, avec, rep, u, v);
    colsum_kernel<<<64, 128, 0, stream>>>(rep, colpart);
    colsum_final<<<1, 128, 0, stream>>>(colpart, colsum);
    attention_kernel<<<N_NODES, 128, 0, stream>>>(rowptr, colidx, u, v, rep,
                                                  colsum, hp_out);
    heads_kernel<<<N_NODES / 8, 128, 0, stream>>>(hp_out, rep, t,
                                                  ppW, ppB, pp2W, pp2B,
                                                  t00W, t00B, t10W, t10B,
                                                  t01W, t01B, t11W, t11B,
                                                  y_out, tr_out);
}

// Round 4
// 192.258 us; speedup vs baseline: 2.3973x; 1.1357x over previous
//
#include <hip/hip_runtime.h>
#include <cstdint>
#include <cstddef>

#define N_NODES 8192
#define NFEAT   512
#define NHID    128

typedef unsigned short u16;
typedef __attribute__((ext_vector_type(8))) short bf16x8;
typedef __attribute__((ext_vector_type(4))) float f32x4;

// bf16 round-to-nearest-even, finite inputs
__device__ inline u16 f2bf(float f) {
    unsigned int u = __float_as_uint(f);
    unsigned int r = (u + 0x7FFFu + ((u >> 16) & 1u)) >> 16;
    return (u16)r;
}
__device__ inline float bf2f(u16 h) {
    return __uint_as_float(((unsigned int)h) << 16);
}

// ---------------------------------------------------------------------------
// Workspace layout (bytes):
//   [0]          bitmap    : 8192*8192/8 = 8388608   (zeroed by zero_ws)
//   [8388608]    cnt       : 32768                    (zeroed)
//   ZERO_BYTES = 8421376
//   [8421376]    rep_preh  : 8192*256*2 = 4194304    (bf16)
//   [12615680]   rep       : 8192*256*4 = 8388608    (f32)
//   [21004288]   rep_t_h   : 8192*128*2 = 2097152    (bf16 twin of treatment half)
//   [23101440]   u         : 32768
//   [23134208]   v         : 32768
//   [23166976]   rowptr    : 33280
//   [23200256]   colidx    : 1048576
//   [24248832]   colpart   : 256*128*4 = 131072
//   [24379904]   colsum    : 512
// ---------------------------------------------------------------------------

// ============ K0: zero bitmap+cnt =========================================
__global__ __launch_bounds__(256)
void zero_ws(uint4* __restrict__ p, int n16)
{
    const uint4 z = make_uint4(0u, 0u, 0u, 0u);
    for (int i = blockIdx.x * blockDim.x + threadIdx.x; i < n16;
         i += gridDim.x * blockDim.x)
        p[i] = z;
}

// ============ K1: rep_preh = bf16( x @ [gc_W | gct_W] ) via MFMA ===========
// Tile 64x64, BK=32, 4 waves of 32x32 (2x2 frags of 16x16x32).
__global__ __launch_bounds__(256)
void gemm_mfma(const float* __restrict__ x,
               const float* __restrict__ gcW,
               const float* __restrict__ gctW,
               u16* __restrict__ rep_preh)
{
    const int bx   = blockIdx.x;          // 0..3  (64-col N tiles of 256)
    const int by   = blockIdx.y;          // 0..127
    const int tid  = threadIdx.x;
    const int lane = tid & 63;
    const int wid  = tid >> 6;            // 0..3
    const int wr   = wid >> 1, wc = wid & 1;
    const float* W = (bx < 2) ? gcW : gctW;
    const int n0w  = (bx & 1) * 64;
    const int row0 = by * 64;

    // +8 pad -> row stride 80B: b128 frag reads land 2-way (free)
    __shared__ __align__(16) u16 Ash[64][40];   // [m][k]
    __shared__ __align__(16) u16 Bsh[64][40];   // [n][k] (transposed W tile)

    f32x4 acc[2][2];
#pragma unroll
    for (int i = 0; i < 2; ++i)
#pragma unroll
        for (int j = 0; j < 2; ++j) acc[i][j] = (f32x4){0.f, 0.f, 0.f, 0.f};

    const int sr = tid >> 2;      // 0..63
    const int sq = tid & 3;       // k-quad: sq*8

    const int fr = lane & 15;     // frag row/col
    const int fq = lane >> 4;     // k-group: fq*8

    for (int k0 = 0; k0 < NFEAT; k0 += 32) {
        // stage A: x[row0+sr][k0+sq*8 .. +8] -> bf16
        {
            const float* src = x + (size_t)(row0 + sr) * NFEAT + k0 + sq * 8;
            const float4 a0 = *reinterpret_cast<const float4*>(src);
            const float4 a1 = *reinterpret_cast<const float4*>(src + 4);
            union { u16 s[8]; bf16x8 v; } pk;
            pk.s[0] = f2bf(a0.x); pk.s[1] = f2bf(a0.y);
            pk.s[2] = f2bf(a0.z); pk.s[3] = f2bf(a0.w);
            pk.s[4] = f2bf(a1.x); pk.s[5] = f2bf(a1.y);
            pk.s[6] = f2bf(a1.z); pk.s[7] = f2bf(a1.w);
            *reinterpret_cast<bf16x8*>(&Ash[sr][sq * 8]) = pk.v;
        }
        // stage B transposed: W[k0+sq*8+j][n0w+sr] -> Bsh[sr][sq*8+j]
        {
            const float* wsrc = W + (size_t)(k0 + sq * 8) * NHID + n0w + sr;
            union { u16 s[8]; bf16x8 v; } pk;
#pragma unroll
            for (int j = 0; j < 8; ++j)
                pk.s[j] = f2bf(wsrc[(size_t)j * NHID]);
            *reinterpret_cast<bf16x8*>(&Bsh[sr][sq * 8]) = pk.v;
        }
        __syncthreads();

        const bf16x8 a0 = *reinterpret_cast<const bf16x8*>(&Ash[wr * 32 + fr][fq * 8]);
        const bf16x8 a1 = *reinterpret_cast<const bf16x8*>(&Ash[wr * 32 + 16 + fr][fq * 8]);
        const bf16x8 b0 = *reinterpret_cast<const bf16x8*>(&Bsh[wc * 32 + fr][fq * 8]);
        const bf16x8 b1 = *reinterpret_cast<const bf16x8*>(&Bsh[wc * 32 + 16 + fr][fq * 8]);
        acc[0][0] = __builtin_amdgcn_mfma_f32_16x16x32_bf16(a0, b0, acc[0][0], 0, 0, 0);
        acc[0][1] = __builtin_amdgcn_mfma_f32_16x16x32_bf16(a0, b1, acc[0][1], 0, 0, 0);
        acc[1][0] = __builtin_amdgcn_mfma_f32_16x16x32_bf16(a1, b0, acc[1][0], 0, 0, 0);
        acc[1][1] = __builtin_amdgcn_mfma_f32_16x16x32_bf16(a1, b1, acc[1][1], 0, 0, 0);
        __syncthreads();
    }

    // C layout (m89-verified): col = lane&15, row = (lane>>4)*4 + reg
    const int gr = row0 + wr * 32 + fq * 4;
    const int gc = bx * 64 + wc * 32 + fr;
#pragma unroll
    for (int mi = 0; mi < 2; ++mi)
#pragma unroll
        for (int ni = 0; ni < 2; ++ni)
#pragma unroll
            for (int i = 0; i < 4; ++i)
                rep_preh[(size_t)(gr + mi * 16 + i) * 256 + gc + ni * 16] =
                    f2bf(acc[mi][ni][i]);
}

// ============ K2: edge dedup (bitmap ownership + row counts) ================
__global__ void edge_pass1(const int* __restrict__ ei, int E,
                           unsigned int* __restrict__ bitmap,
                           int* __restrict__ cnt)
{
    const int e = blockIdx.x * blockDim.x + threadIdx.x;
    if (e >= E) return;
    const int s = ei[e];
    const int d = ei[E + e];
    const unsigned int idx  = (unsigned int)s * 8192u + (unsigned int)d;
    const unsigned int mask = 1u << (idx & 31u);
    const unsigned int old  = atomicOr(&bitmap[idx >> 5], mask);
    if ((old & mask) == 0u) atomicAdd(&cnt[s], 1);  // int add: deterministic
}

// ============ K3: exclusive scan of cnt -> rowptr (single block) ============
__global__ __launch_bounds__(1024)
void scan_kernel(const int* __restrict__ cnt, int* __restrict__ rowptr)
{
    __shared__ int part[1024];
    const int tid = threadIdx.x;
    int loc[8];
    int s = 0;
#pragma unroll
    for (int j = 0; j < 8; ++j) { loc[j] = cnt[tid * 8 + j]; s += loc[j]; }
    part[tid] = s;
    __syncthreads();
    for (int off = 1; off < 1024; off <<= 1) {
        const int val = (tid >= off) ? part[tid - off] : 0;
        __syncthreads();
        part[tid] += val;
        __syncthreads();
    }
    int run = (tid == 0) ? 0 : part[tid - 1];
#pragma unroll
    for (int j = 0; j < 8; ++j) { rowptr[tid * 8 + j] = run; run += loc[j]; }
    if (tid == 1023) rowptr[8192] = run;
}

// ============ K4: extract sorted columns straight from the bitmap ===========
__global__ __launch_bounds__(64)
void bitmap_extract(const unsigned int* __restrict__ bitmap,
                    const int* __restrict__ rowptr,
                    int* __restrict__ colidx)
{
    const int row  = blockIdx.x;
    const int lane = threadIdx.x;
    const uint4 w = *reinterpret_cast<const uint4*>(
        bitmap + (size_t)row * 256 + lane * 4);
    const int c = __popc(w.x) + __popc(w.y) + __popc(w.z) + __popc(w.w);
    int off = c;
    for (int d = 1; d < 64; d <<= 1) {
        const int n = __shfl_up(off, d, 64);
        if (lane >= d) off += n;
    }
    off -= c;
    int pos = rowptr[row] + off;
    const int base = lane * 128;
    unsigned int wv[4] = {w.x, w.y, w.z, w.w};
#pragma unroll
    for (int j = 0; j < 4; ++j) {
        unsigned int b = wv[j];
        while (b) {
            const int bit = __ffs(b) - 1;
            colidx[pos++] = base + j * 32 + bit;
            b &= b - 1;
        }
    }
}

// ============ K5: CSR aggregate (bf16 gather) + bias + relu ================
__global__ __launch_bounds__(256)
void aggregate_kernel(const u16* __restrict__ rep_preh,
                      const int* __restrict__ rowptr,
                      const int* __restrict__ colidx,
                      const float* __restrict__ gcB,
                      const float* __restrict__ gctB,
                      const float* __restrict__ avec,
                      float* __restrict__ rep,
                      u16* __restrict__ rep_t_h,
                      float* __restrict__ u,
                      float* __restrict__ v)
{
    const int i   = blockIdx.x;
    const int tid = threadIdx.x;
    const int rp  = rowptr[i];
    const int rpe = rowptr[i + 1];
    float acc = 0.f;
    for (int p = rp; p < rpe; ++p)
        acc += bf2f(rep_preh[(size_t)colidx[p] * 256 + tid]);
    const float bias = (tid < 128) ? gcB[tid] : gctB[tid - 128];
    const float val  = fmaxf(acc + bias, 0.f);
    rep[(size_t)i * 256 + tid] = val;
    if (tid >= 128) rep_t_h[(size_t)i * 128 + tid - 128] = f2bf(val);

    __shared__ float su[256], sv[256];
    su[tid] = avec[tid] * val;
    sv[tid] = avec[256 + tid] * val;
    __syncthreads();
#pragma unroll
    for (int s = 128; s > 0; s >>= 1) {
        if (tid < s) { su[tid] += su[tid + s]; sv[tid] += sv[tid + s]; }
        __syncthreads();
    }
    if (tid == 0) { u[i] = su[0]; v[i] = sv[0]; }
}

// ============ K6: colsum of rep_t (deterministic two-stage, wide) ===========
__global__ __launch_bounds__(128)
void colsum_kernel(const u16* __restrict__ rep_t_h, float* __restrict__ colpart)
{
    const int f = threadIdx.x;
    const int b = blockIdx.x;          // 0..255, 32 rows each
    const int r0 = b * 32;
    float s = 0.f;
    for (int r = 0; r < 32; ++r)
        s += bf2f(rep_t_h[(size_t)(r0 + r) * 128 + f]);
    colpart[b * 128 + f] = s;
}

__global__ __launch_bounds__(128)
void colsum_final(const float* __restrict__ colpart, float* __restrict__ colsum)
{
    const int f = threadIdx.x;
    float s = 0.f;
    for (int b = 0; b < 256; ++b) s += colpart[b * 128 + f];
    colsum[f] = s;
}

// ============ K7: per-row attention + residual -> h_prime ===================
__global__ __launch_bounds__(128)
void attention_kernel(const int* __restrict__ rowptr,
                      const int* __restrict__ colidx,
                      const float* __restrict__ u,
                      const float* __restrict__ v,
                      const u16* __restrict__ rep_t_h,
                      const float* __restrict__ rep,
                      const float* __restrict__ colsum,
                      float* __restrict__ hp_out)
{
    const int i   = blockIdx.x;
    const int tid = threadIdx.x;
    const int rp  = rowptr[i];
    const int deg = rowptr[i + 1] - rp;
    const float ui = u[i];

    __shared__ float red[128];
    __shared__ float wsh[128];
    __shared__ int   csh[128];

    float mloc = -1e30f;
    for (int p = tid; p < deg; p += 128)
        mloc = fmaxf(mloc, ui + v[colidx[rp + p]]);
    red[tid] = mloc;
    __syncthreads();
#pragma unroll
    for (int s = 64; s > 0; s >>= 1) {
        if (tid < s) red[tid] = fmaxf(red[tid], red[tid + s]);
        __syncthreads();
    }
    const float m = fmaxf(red[0], 0.f);
    __syncthreads();
    const float e0 = expf(-m);

    float Zloc = 0.f;
    float acc  = 0.f;
    for (int base = 0; base < deg; base += 128) {
        const int p = base + tid;
        if (p < deg) {
            const int c = colidx[rp + p];
            csh[tid] = c;
            const float w = expf(ui + v[c] - m);
            wsh[tid] = w;
            Zloc += w;
        }
        __syncthreads();
        const int cnt2 = min(128, deg - base);
        for (int q = 0; q < cnt2; ++q)
            acc += (wsh[q] - e0) * bf2f(rep_t_h[(size_t)csh[q] * 128 + tid]);
        __syncthreads();
    }
    red[tid] = Zloc;
    __syncthreads();
#pragma unroll
    for (int s = 64; s > 0; s >>= 1) {
        if (tid < s) red[tid] += red[tid + s];
        __syncthreads();
    }
    const float Z  = red[0] + (8192.f - (float)deg) * e0;
    const float hv = (acc + e0 * colsum[tid]) / Z + rep[(size_t)i * 256 + tid];
    hp_out[(size_t)i * 128 + tid] = hv;
}

// ============ K8: output heads (treatment / y0 / y1 / select) ===============
__global__ __launch_bounds__(128)
void heads_kernel(const float* __restrict__ hprime,   // [N,128]
                  const float* __restrict__ rep,      // [N,256]
                  const int* __restrict__ t,
                  const float* __restrict__ ppW,  const float* __restrict__ ppB,
                  const float* __restrict__ pp2W, const float* __restrict__ pp2B,
                  const float* __restrict__ t00W, const float* __restrict__ t00B,
                  const float* __restrict__ t10W, const float* __restrict__ t10B,
                  const float* __restrict__ t01W, const float* __restrict__ t01B,
                  const float* __restrict__ t11W, const float* __restrict__ t11B,
                  float* __restrict__ y_out,
                  float* __restrict__ treat_out)
{
    const int f  = threadIdx.x;
    const int r0 = blockIdx.x * 8;
    __shared__ float hs[8][128];
    __shared__ float ts[8][128];
#pragma unroll
    for (int r = 0; r < 8; ++r) {
        hs[r][f] = hprime[(size_t)(r0 + r) * 128 + f];
        ts[r][f] = rep[(size_t)(r0 + r) * 256 + 128 + f];
    }
    __syncthreads();

    float a00[8], a10[8], app[8];
#pragma unroll
    for (int r = 0; r < 8; ++r) { a00[r] = 0.f; a10[r] = 0.f; app[r] = 0.f; }

    for (int k = 0; k < 128; ++k) {
        const float w00 = t00W[k * 128 + f];
        const float w10 = t10W[k * 128 + f];
        const float wpp = ppW [k * 128 + f];
#pragma unroll
        for (int r = 0; r < 8; ++r) {
            a00[r] += hs[r][k] * w00;
            a10[r] += hs[r][k] * w10;
            app[r] += ts[r][k] * wpp;
        }
    }
    __syncthreads();

    const float b00 = t00B[f], b10 = t10B[f], bpp = ppB[f];
    const float w01 = t01W[f], w11 = t11W[f];
    const float w20 = pp2W[2 * f + 0], w21 = pp2W[2 * f + 1];

    for (int r = 0; r < 8; ++r) {
        __syncthreads();
        const float h00 = fmaxf(a00[r] + b00, 0.f);
        const float h10 = fmaxf(a10[r] + b10, 0.f);
        const float hp2 = app[r] + bpp;
        hs[0][f] = h00 * w01;
        hs[1][f] = h10 * w11;
        hs[2][f] = hp2 * w20;
        hs[3][f] = hp2 * w21;
        __syncthreads();
#pragma unroll
        for (int s = 64; s > 0; s >>= 1) {
            if (f < s) {
                hs[0][f] += hs[0][f + s];
                hs[1][f] += hs[1][f + s];
                hs[2][f] += hs[2][f + s];
                hs[3][f] += hs[3][f + s];
            }
            __syncthreads();
        }
        if (f == 0) {
            const int node = r0 + r;
            const float y0 = hs[0][0] + t01B[0];
            const float y1 = hs[1][0] + t11B[0];
            y_out[node] = (t[node] > 0) ? y1 : y0;
            const float tr0 = hs[2][0] + pp2B[0];
            const float tr1 = hs[3][0] + pp2B[1];
            treat_out[node * 2 + 0] = 1.f / (1.f + expf(-tr0));
            treat_out[node * 2 + 1] = 1.f / (1.f + expf(-tr1));
        }
    }
}

// ===========================================================================
extern "C" void kernel_launch(void* const* d_in, const int* in_sizes, int n_in,
                              void* d_out, int out_size, void* d_ws, size_t ws_size,
                              hipStream_t stream)
{
    const float* x    = (const float*)d_in[0];
    // d_in[1] = dense adj : intentionally unused (structure rebuilt from edges)
    const int*   ei   = (const int*)d_in[2];
    const int*   t    = (const int*)d_in[3];
    const float* gcW  = (const float*)d_in[4];
    const float* gcB  = (const float*)d_in[5];
    const float* gctW = (const float*)d_in[6];
    const float* gctB = (const float*)d_in[7];
    const float* avec = (const float*)d_in[8];
    const float* ppW  = (const float*)d_in[9];
    const float* ppB  = (const float*)d_in[10];
    const float* pp2W = (const float*)d_in[11];
    const float* pp2B = (const float*)d_in[12];
    const float* t00W = (const float*)d_in[13];
    const float* t00B = (const float*)d_in[14];
    const float* t10W = (const float*)d_in[15];
    const float* t10B = (const float*)d_in[16];
    const float* t01W = (const float*)d_in[17];
    const float* t01B = (const float*)d_in[18];
    const float* t11W = (const float*)d_in[19];
    const float* t11B = (const float*)d_in[20];

    const int E = in_sizes[2] / 2;

    char* ws = (char*)d_ws;
    unsigned int*  bitmap   = (unsigned int*) (ws + 0);
    int*           cnt      = (int*)          (ws + 8388608);
    const size_t   ZERO_BYTES = 8421376;     // bitmap + cnt
    u16*           rep_preh = (u16*)          (ws + 8421376);
    float*         rep      = (float*)        (ws + 12615680);
    u16*           rep_t_h  = (u16*)          (ws + 21004288);
    float*         u        = (float*)        (ws + 23101440);
    float*         v        = (float*)        (ws + 23134208);
    int*           rowptr   = (int*)          (ws + 23166976);
    int*           colidx   = (int*)          (ws + 23200256);
    float*         colpart  = (float*)        (ws + 24248832);
    float*         colsum   = (float*)        (ws + 24379904);

    float* y_out  = (float*)d_out;
    float* hp_out = (float*)d_out + N_NODES;
    float* tr_out = (float*)d_out + N_NODES + (size_t)N_NODES * NHID;

    zero_ws<<<2048, 256, 0, stream>>>((uint4*)ws, (int)(ZERO_BYTES / 16));

    gemm_mfma<<<dim3(4, 128), 256, 0, stream>>>(x, gcW, gctW, rep_preh);
    edge_pass1<<<(E + 255) / 256, 256, 0, stream>>>(ei, E, bitmap, cnt);
    scan_kernel<<<1, 1024, 0, stream>>>(cnt, rowptr);
    bitmap_extract<<<N_NODES, 64, 0, stream>>>(bitmap, rowptr, colidx);
    aggregate_kernel<<<N_NODES, 256, 0, stream>>>(rep_preh, rowptr, colidx,
                                                  gcB, gctB, avec, rep, rep_t_h, u, v);
    colsum_kernel<<<256, 128, 0, stream>>>(rep_t_h, colpart);
    colsum_final<<<1, 128, 0, stream>>>(colpart, colsum);
    attention_kernel<<<N_NODES, 128, 0, stream>>>(rowptr, colidx, u, v, rep_t_h,
                                                  rep, colsum, hp_out);
    heads_kernel<<<N_NODES / 8, 128, 0, stream>>>(hp_out, rep, t,
                                                  ppW, ppB, pp2W, pp2B,
                                                  t00W, t00B, t10W, t10B,
                                                  t01W, t01B, t11W, t11B,
                                                  y_out, tr_out);
}